// Round 14
// baseline (242.523 us; speedup 1.0000x reference)
//
#include <hip/hip_runtime.h>
#include <hip/hip_bf16.h>

typedef float f32x4 __attribute__((ext_vector_type(4)));
typedef short bf16x8 __attribute__((ext_vector_type(8)));

#define MFMA_BF16 __builtin_amdgcn_mfma_f32_16x16x32_bf16

static __device__ __forceinline__ unsigned short f2bf(float f) {
    __hip_bfloat16 h = __float2bfloat16(f);
    return __builtin_bit_cast(unsigned short, h);
}
static __device__ __forceinline__ unsigned int pack2(float a, float b) {
    return (unsigned int)f2bf(a) | ((unsigned int)f2bf(b) << 16);
}

// Async global->LDS, 16B per lane. LDS dest is wave-uniform base + lane*16.
static __device__ __forceinline__ void gl16(const unsigned short* g, unsigned short* l) {
    unsigned short* gg = const_cast<unsigned short*>(g);
    __builtin_amdgcn_global_load_lds(
        (__attribute__((address_space(1))) unsigned int*)gg,
        (__attribute__((address_space(3))) unsigned int*)l, 16, 0, 0);
}

// ---------------------------------------------------------------------------
// Merged prep: blocks 0..1023 transpose W (f32 k-major -> bf16 n-major);
// blocks 1024..7167 convert q/k/v f32 -> bf16. One launch instead of two.
// ---------------------------------------------------------------------------
__global__ __launch_bounds__(256) void prep_kernel(
    const float* __restrict__ q, const float* __restrict__ k, const float* __restrict__ v,
    const float* __restrict__ Wq, const float* __restrict__ Wk,
    const float* __restrict__ Wv, const float* __restrict__ Wo,
    unsigned short* __restrict__ WT, unsigned short* __restrict__ qkvb)
{
    const int bid = blockIdx.x;
    const int t = threadIdx.x;
    if (bid < 1024) {
        // conv_wT tile
        const int z = bid >> 8, rem = bid & 255;
        const int k0 = (rem & 15) * 64, n0 = (rem >> 4) * 64;
        const float* W = (z == 0) ? Wq : (z == 1) ? Wk : (z == 2) ? Wv : Wo;
        unsigned short* Wt = WT + (size_t)z * 1048576;
        __shared__ float tl[64][68];
        const int r = t >> 2, cs = (t & 3) * 16;
#pragma unroll
        for (int j = 0; j < 4; j++)
            *(float4*)&tl[r][cs + j * 4] = *(const float4*)&W[(size_t)(k0 + r) * 1024 + n0 + cs + j * 4];
        __syncthreads();
        const int n = t & 63, kb = (t >> 6) * 16;
#pragma unroll
        for (int j = 0; j < 4; j++) {
            const int kk = kb + j * 4;
            uint2 o = { pack2(tl[kk][n], tl[kk + 1][n]), pack2(tl[kk + 2][n], tl[kk + 3][n]) };
            *(uint2*)&Wt[(size_t)(n0 + n) * 1024 + k0 + kk] = o;
        }
    } else {
        const int idx = bid - 1024;           // 0..6143
        const int z = idx >> 11;              // /2048
        const int xb = idx & 2047;
        const float* s = (z == 0) ? q : (z == 1) ? k : v;
        unsigned short* d = qkvb + (size_t)z * 4194304;
        const size_t i = ((size_t)xb * 256 + t) * 8;
        float4 a = *(const float4*)&s[i], b = *(const float4*)&s[i + 4];
        uint4 o = { pack2(a.x, a.y), pack2(a.z, a.w), pack2(b.x, b.y), pack2(b.z, b.w) };
        *(uint4*)&d[i] = o;
    }
}

// ---------------------------------------------------------------------------
// Shared GEMM core v2: C(128x128) = A(row-major [M][1024] bf16) x Bt^T.
// Triple-buffered LDS, depth-2 prefetch, counted vmcnt(4) + raw barrier.
// ---------------------------------------------------------------------------
static __device__ __forceinline__ void gemm_core(
    const unsigned short* __restrict__ A, const unsigned short* __restrict__ Bt,
    unsigned short* lA, unsigned short* lB, int m0, int n0, f32x4 (&acc)[4][4])
{
    const int t = threadIdx.x;
    const int w = t >> 6, lane = t & 63, lrow = lane & 15, lkg = lane >> 4;
    const int wr = w >> 1, wc = w & 1;
    const int srow = lane >> 2, sseg = (lane & 3) * 8;

    const unsigned short* Ab0 = &A[(size_t)(m0 + w * 32 + srow) * 1024 + sseg];
    const unsigned short* Ab1 = &A[(size_t)(m0 + w * 32 + 16 + srow) * 1024 + sseg];
    const unsigned short* Bb0 = &Bt[(size_t)(n0 + w * 32 + srow) * 1024 + sseg];
    const unsigned short* Bb1 = &Bt[(size_t)(n0 + w * 32 + 16 + srow) * 1024 + sseg];

#define GISSUE(tt, buf)                                     \
    do {                                                    \
        const int k0_ = (tt) * 32;                          \
        gl16(Ab0 + k0_, &lA[(buf) * 4096 + w * 1024]);      \
        gl16(Ab1 + k0_, &lA[(buf) * 4096 + w * 1024 + 512]);\
        gl16(Bb0 + k0_, &lB[(buf) * 4096 + w * 1024]);      \
        gl16(Bb1 + k0_, &lB[(buf) * 4096 + w * 1024 + 512]);\
    } while (0)

    GISSUE(0, 0);
    GISSUE(1, 1);
    __builtin_amdgcn_sched_barrier(0);

    int bcur = 0;
    for (int tt = 0; tt < 32; ++tt) {
        if (tt < 31) { asm volatile("s_waitcnt vmcnt(4)"); }
        else         { asm volatile("s_waitcnt vmcnt(0)"); }
        __builtin_amdgcn_s_barrier();
        __builtin_amdgcn_sched_barrier(0);
        if (tt + 2 < 32) {
            int bpre = bcur + 2; if (bpre >= 3) bpre -= 3;
            GISSUE(tt + 2, bpre);
        }
        __builtin_amdgcn_sched_barrier(0);

        const unsigned short* la = &lA[bcur * 4096];
        const unsigned short* lb = &lB[bcur * 4096];
        bf16x8 af[4], bfr[4];
#pragma unroll
        for (int mi = 0; mi < 4; mi++)
            af[mi] = *(const bf16x8*)&la[(wr * 64 + mi * 16 + lrow) * 32 + lkg * 8];
#pragma unroll
        for (int ni = 0; ni < 4; ni++)
            bfr[ni] = *(const bf16x8*)&lb[(wc * 64 + ni * 16 + lrow) * 32 + lkg * 8];
        __builtin_amdgcn_s_setprio(1);
#pragma unroll
        for (int mi = 0; mi < 4; mi++)
#pragma unroll
            for (int ni = 0; ni < 4; ni++)
                acc[mi][ni] = MFMA_BF16(af[mi], bfr[ni], acc[mi][ni], 0, 0, 0);
        __builtin_amdgcn_s_setprio(0);
        bcur = (bcur == 2) ? 0 : bcur + 1;
    }
#undef GISSUE
}

// ---------------------------------------------------------------------------
// QKV projections, 1D XCD-chunked grid (768 = 8 XCD x 96).
// z=0: Q->[B,H,L,64]; z=1: K->[B,H,L,64]; z=2: V->[B,H,64,L].
// ---------------------------------------------------------------------------
__global__ __launch_bounds__(256) void gemm_qkv(
    const unsigned short* __restrict__ qkvb, const unsigned short* __restrict__ WT,
    const float* __restrict__ bq, const float* __restrict__ bk, const float* __restrict__ bv,
    unsigned short* __restrict__ Qh, unsigned short* __restrict__ Kh, unsigned short* __restrict__ Vt)
{
    const int u0 = blockIdx.x;
    const int u = (u0 & 7) * 96 + (u0 >> 3);       // XCD-contiguous chunks
    const int z = u >> 8, rm = u & 255;
    const int m0 = ((rm >> 3) & 31) * 128, n0 = (rm & 7) * 128;

    const unsigned short* A = qkvb + (size_t)z * 4194304;
    const unsigned short* Bt = WT + (size_t)z * 1048576;
    const float* bias = (z == 0) ? bq : (z == 1) ? bk : bv;

    __shared__ unsigned short lA[3 * 4096], lB[3 * 4096];
    f32x4 acc[4][4];
#pragma unroll
    for (int i = 0; i < 4; i++)
#pragma unroll
        for (int j = 0; j < 4; j++) acc[i][j] = (f32x4){0.f, 0.f, 0.f, 0.f};

    gemm_core(A, Bt, lA, lB, m0, n0, acc);

    const int t = threadIdx.x;
    const int w = t >> 6, lane = t & 63, lrow = lane & 15, lkg = lane >> 4;
    const int wr = w >> 1, wc = w & 1;

#pragma unroll
    for (int mi = 0; mi < 4; mi++) {
#pragma unroll
        for (int ni = 0; ni < 4; ni++) {
            const int gn = n0 + wc * 64 + ni * 16 + lrow;
            const float bb = bias[gn];
            const int hh = gn >> 6, dk = gn & 63;
            const int gm0 = m0 + wr * 64 + mi * 16 + lkg * 4;
            const int b2 = gm0 >> 11, ll = gm0 & 2047;
            if (z < 2) {
                unsigned short* C = (z == 0) ? Qh : Kh;
#pragma unroll
                for (int r = 0; r < 4; r++)
                    C[(size_t)((b2 * 16 + hh) * 2048 + ll + r) * 64 + dk] = f2bf(acc[mi][ni][r] + bb);
            } else {
                uint2 o = { pack2(acc[mi][ni][0] + bb, acc[mi][ni][1] + bb),
                            pack2(acc[mi][ni][2] + bb, acc[mi][ni][3] + bb) };
                *(uint2*)&Vt[(size_t)((b2 * 16 + hh) * 64 + dk) * 2048 + ll] = o;
            }
        }
    }
}

// ---------------------------------------------------------------------------
// Output projection, 1D XCD-chunked grid (256 = 8 x 32).
// ---------------------------------------------------------------------------
__global__ __launch_bounds__(256) void gemm_o(
    const unsigned short* __restrict__ Oh, const unsigned short* __restrict__ WoT,
    const float* __restrict__ bo, float* __restrict__ out)
{
    const int u0 = blockIdx.x;
    const int u = (u0 & 7) * 32 + (u0 >> 3);
    const int m0 = (u >> 3) * 128, n0 = (u & 7) * 128;

    __shared__ unsigned short lA[3 * 4096], lB[3 * 4096];
    f32x4 acc[4][4];
#pragma unroll
    for (int i = 0; i < 4; i++)
#pragma unroll
        for (int j = 0; j < 4; j++) acc[i][j] = (f32x4){0.f, 0.f, 0.f, 0.f};

    gemm_core(Oh, WoT, lA, lB, m0, n0, acc);

    const int t = threadIdx.x;
    const int w = t >> 6, lane = t & 63, lrow = lane & 15, lkg = lane >> 4;
    const int wr = w >> 1, wc = w & 1;

#pragma unroll
    for (int mi = 0; mi < 4; mi++) {
#pragma unroll
        for (int ni = 0; ni < 4; ni++) {
            const int gn = n0 + wc * 64 + ni * 16 + lrow;
            const float bb = bo[gn];
            const int gm0 = m0 + wr * 64 + mi * 16 + lkg * 4;
#pragma unroll
            for (int r = 0; r < 4; r++)
                out[(size_t)(gm0 + r) * 1024 + gn] = acc[mi][ni][r] + bb;
        }
    }
}

// ---------------------------------------------------------------------------
// Fused attention v5: Q-tile 64, 4 waves, 1024 blocks.
// LDS 48KB: regA 16KB (sweep1 buf0 / sweep2 f32 stage) + kv 32KB (sweep1
// buf1 uses kv0; sweep2 K+V DOUBLE buffer kv0/kv1) -> 3 blocks/CU.
// Sweep 1: KVBLK=128 dbuf regA/kv0, 16 tiles, 1 barrier each.
// Sweep 2 (wait-at-top schedule): per tile t:
//   vmcnt(4) [t=0: vmcnt(0)] -> retires loads(t) (oldest); stores(t-1),
//   issued AFTER loads(t), stay in flight; s_barrier; issue loads(t+1) into
//   the other kv buffer; QK -> exp->stage -> PV; transposed 256B nt-stores.
//   ONE barrier per tile; loads get a full tile of latency cover; stores
//   are never explicitly waited (retire lazily 2 tiles later).
// ---------------------------------------------------------------------------
__global__ __launch_bounds__(256, 3) void attn_kernel(
    const unsigned short* __restrict__ Qh, const unsigned short* __restrict__ Kh,
    const unsigned short* __restrict__ Vt, float* __restrict__ attn,
    unsigned short* __restrict__ Oh)
{
    const int bid = blockIdx.x;
    const int swz = (bid & 7) * 128 + (bid >> 3);    // XCD-contiguous (1024 = 8*128)
    const int bh = swz >> 5;
    const int q0 = (swz & 31) * 64;
    const int b = bh >> 4, h = bh & 15;
    const int t = threadIdx.x;
    const int w = t >> 6, lane = t & 63, ql = lane & 15, kg = lane >> 4;

    __shared__ unsigned short regA[8192];    // 16KB
    __shared__ unsigned short kv[16384];     // 32KB: kv0 = +0, kv1 = +8192

    const size_t kvbase = (size_t)bh * 2048 * 64;
    const float C = 0.18033688011112042f;    // 0.125 * log2(e)

    const unsigned short* qptr = Qh + kvbase + (size_t)(q0 + w * 16 + ql) * 64 + kg * 8;
    const bf16x8 qf0 = *(const bf16x8*)(qptr);
    const bf16x8 qf1 = *(const bf16x8*)(qptr + 32);

    const unsigned short* Kbh = Kh + kvbase;
    const unsigned short* Vbh = Vt + kvbase;

    // sweep-2 staging coords: wave w covers rows kr, kr+8 (pre-swizzled col16)
    const int kr = w * 16 + (lane >> 3);
    const int kc = (lane & 7) ^ (kr & 7);
    // sweep-1 staging coords: wave w covers rows kr2 + 8i, i=0..3 (128-row tile)
    const int kr2 = w * 32 + (lane >> 3);
    const int kc2 = (lane & 7) ^ (kr2 & 7);
    const int r7 = ql & 7;

    unsigned short* kv0 = &kv[0];
    unsigned short* kv1 = &kv[8192];

    // ---- sweep 1: denominators (K tiles of 128 rows, dbuf regA/kv0) ----
    f32x4 ls4 = (f32x4){0.f, 0.f, 0.f, 0.f};
    {
#pragma unroll
        for (int i = 0; i < 4; i++)
            gl16(Kbh + (size_t)(kr2 + 8 * i) * 64 + kc2 * 8, &regA[w * 2048 + i * 512]);
        __syncthreads();
        for (int kt = 0; kt < 16; ++kt) {
            unsigned short* nbuf = (kt & 1) ? regA : kv0;      // dest for tile kt+1
            if (kt < 15) {
                const int k0n = (kt + 1) * 128;
#pragma unroll
                for (int i = 0; i < 4; i++)
                    gl16(Kbh + (size_t)(k0n + kr2 + 8 * i) * 64 + kc2 * 8, &nbuf[w * 2048 + i * 512]);
            }
            const unsigned short* Kl = (kt & 1) ? kv0 : regA;
            f32x4 sacc[8];
            __builtin_amdgcn_s_setprio(1);
#pragma unroll
            for (int ni = 0; ni < 8; ni++) {
                const int rb = (ni * 16 + ql) * 64;
                bf16x8 kf0 = *(const bf16x8*)&Kl[rb + ((kg ^ r7) * 8)];
                bf16x8 kf1 = *(const bf16x8*)&Kl[rb + (((4 + kg) ^ r7) * 8)];
                f32x4 s = (f32x4){0.f, 0.f, 0.f, 0.f};
                s = MFMA_BF16(kf0, qf0, s, 0, 0, 0);
                sacc[ni] = MFMA_BF16(kf1, qf1, s, 0, 0, 0);
            }
            __builtin_amdgcn_s_setprio(0);
#pragma unroll
            for (int ni = 0; ni < 8; ni++)
#pragma unroll
                for (int r = 0; r < 4; r++) ls4[r] += exp2f(sacc[ni][r] * C);
            __syncthreads();
        }
        // issue sweep-2 tile 0 into kv0 (read at kt=15; barrier passed)
        gl16(Kbh + (size_t)kr * 64 + kc * 8, &kv0[w * 1024]);
        gl16(Kbh + (size_t)(kr + 8) * 64 + kc * 8, &kv0[w * 1024 + 512]);
        gl16(Vbh + (size_t)kr * 2048 + kc * 8, &kv0[4096 + w * 1024]);
        gl16(Vbh + (size_t)(kr + 8) * 2048 + kc * 8, &kv0[4096 + w * 1024 + 512]);
        __builtin_amdgcn_sched_barrier(0);
    }
    float lsum = ls4[0] + ls4[1] + ls4[2] + ls4[3];
    lsum += __shfl_xor(lsum, 16);
    lsum += __shfl_xor(lsum, 32);
    const float mlg = -log2f(lsum);          // p = exp2(S*C - log2 l)

    // ---- sweep 2: attn write + PV (K+V tiles of 64, dbuf kv0/kv1) ----
    f32x4 acco[4];
#pragma unroll
    for (int nv = 0; nv < 4; nv++) acco[nv] = (f32x4){0.f, 0.f, 0.f, 0.f};

    float* stgW = (float*)regA + w * 1024;   // per-wave [16 q][64 k] f32 stage
    float* abase = attn + ((size_t)bh * 2048 + q0 + w * 16) * 2048 + ql * 4;

    for (int kt = 0; kt < 32; ++kt) {
        const int k0 = kt * 64;
        // wait-at-top: retire loads(kt) (oldest); stores(kt-1) stay in flight
        if (kt == 0) { asm volatile("s_waitcnt vmcnt(0)"); }
        else         { asm volatile("s_waitcnt vmcnt(4)"); }
        __builtin_amdgcn_s_barrier();
        __builtin_amdgcn_sched_barrier(0);

        unsigned short* cur = (kt & 1) ? kv1 : kv0;
        if (kt < 31) {
            unsigned short* nxt = (kt & 1) ? kv0 : kv1;
            const int k0n = (kt + 1) * 64;
            gl16(Kbh + (size_t)(k0n + kr) * 64 + kc * 8, &nxt[w * 1024]);
            gl16(Kbh + (size_t)(k0n + kr + 8) * 64 + kc * 8, &nxt[w * 1024 + 512]);
            gl16(Vbh + (size_t)kr * 2048 + k0n + kc * 8, &nxt[4096 + w * 1024]);
            gl16(Vbh + (size_t)(kr + 8) * 2048 + k0n + kc * 8, &nxt[4096 + w * 1024 + 512]);
        }
        __builtin_amdgcn_sched_barrier(0);

        const unsigned short* kvK = cur;
        const unsigned short* kvV = cur + 4096;

        // QK^T cluster
        f32x4 sacc[4];
        __builtin_amdgcn_s_setprio(1);
#pragma unroll
        for (int ni = 0; ni < 4; ni++) {
            const int rb = (ni * 16 + ql) * 64;
            bf16x8 kf0 = *(const bf16x8*)&kvK[rb + ((kg ^ r7) * 8)];
            bf16x8 kf1 = *(const bf16x8*)&kvK[rb + (((4 + kg) ^ r7) * 8)];
            f32x4 s = (f32x4){0.f, 0.f, 0.f, 0.f};
            s = MFMA_BF16(kf0, qf0, s, 0, 0, 0);
            sacc[ni] = MFMA_BF16(kf1, qf1, s, 0, 0, 0);
        }
        __builtin_amdgcn_s_setprio(0);

        // exp -> f32 stage (wave-private)
#pragma unroll
        for (int ni = 0; ni < 4; ni++) {
            f32x4 p;
#pragma unroll
            for (int r = 0; r < 4; r++) p[r] = exp2f(fmaf(sacc[ni][r], C, mlg));
            *(f32x4*)&stgW[ql * 64 + ni * 16 + kg * 4] = p;
        }

        // PV: derive bf16 P from stage; O^T += V^T x P^T
        __builtin_amdgcn_s_setprio(1);
#pragma unroll
        for (int s4 = 0; s4 < 2; s4++) {
            const float* ps = &stgW[ql * 64 + s4 * 32 + kg * 8];
            f32x4 pa = *(const f32x4*)ps;
            f32x4 pb = *(const f32x4*)(ps + 4);
            uint4 pw = { pack2(pa[0], pa[1]), pack2(pa[2], pa[3]),
                         pack2(pb[0], pb[1]), pack2(pb[2], pb[3]) };
            bf16x8 pf = __builtin_bit_cast(bf16x8, pw);
#pragma unroll
            for (int nv = 0; nv < 4; nv++) {
                const int cc = (s4 * 4 + kg) ^ r7;
                bf16x8 vf = *(const bf16x8*)&kvV[(nv * 16 + ql) * 64 + cc * 8];
                acco[nv] = MFMA_BF16(vf, pf, acco[nv], 0, 0, 0);
            }
        }
        __builtin_amdgcn_s_setprio(0);

        // transposed attn stores (4 instrs, 4 rows x 256B contiguous each);
        // never explicitly waited — drain across the next two tiles.
#pragma unroll
        for (int i = 0; i < 4; i++) {
            const int row = i * 4 + kg;
            f32x4 vv = *(const f32x4*)&stgW[row * 64 + ql * 4];
            __builtin_nontemporal_store(vv, (f32x4*)&abase[(size_t)row * 2048 + k0]);
        }
    }
    asm volatile("s_waitcnt vmcnt(0)");

    unsigned short* obase = Oh + ((size_t)(b * 2048 + q0 + w * 16 + ql)) * 1024 + h * 64 + kg * 4;
#pragma unroll
    for (int nv = 0; nv < 4; nv++) {
        uint2 o2 = { pack2(acco[nv][0], acco[nv][1]), pack2(acco[nv][2], acco[nv][3]) };
        *(uint2*)&obase[nv * 16] = o2;
    }
}

// ---------------------------------------------------------------------------
extern "C" void kernel_launch(void* const* d_in, const int* in_sizes, int n_in,
                              void* d_out, int out_size, void* d_ws, size_t ws_size,
                              hipStream_t stream) {
    const float* q  = (const float*)d_in[0];
    const float* k  = (const float*)d_in[1];
    const float* v  = (const float*)d_in[2];
    const float* Wq = (const float*)d_in[3];
    const float* bq = (const float*)d_in[4];
    const float* Wk = (const float*)d_in[5];
    const float* bk = (const float*)d_in[6];
    const float* Wv = (const float*)d_in[7];
    const float* bv = (const float*)d_in[8];
    const float* Wo = (const float*)d_in[9];
    const float* bo = (const float*)d_in[10];

    float* out  = (float*)d_out;                    // [2,2048,1024]
    float* attn = out + (size_t)2 * 2048 * 1024;    // [2,16,2048,2048]

    const size_t HS = 4194304;                      // 2*16*2048*64
    unsigned short* qkvb = (unsigned short*)d_ws;   // 3*HS bf16
    unsigned short* WT   = qkvb + 3 * HS;           // 4 * 1M bf16
    unsigned short* Qh   = WT + 4 * 1048576;        // [B,H,L,64]
    unsigned short* Kh   = Qh + HS;                 // [B,H,L,64]
    unsigned short* Vt   = Kh + HS;                 // [B,H,64,L]
    unsigned short* Oh   = Vt + HS;                 // [B,L,1024]

    prep_kernel<<<dim3(7168), 256, 0, stream>>>(q, k, v, Wq, Wk, Wv, Wo, WT, qkvb);
    gemm_qkv   <<<dim3(768),  256, 0, stream>>>(qkvb, WT, bq, bk, bv, Qh, Kh, Vt);
    attn_kernel<<<dim3(1024), 256, 0, stream>>>(Qh, Kh, Vt, attn, Oh);
    gemm_o     <<<dim3(256),  256, 0, stream>>>(Oh, WT + 3 * 1048576, bo, out);
}

// Round 15
// 233.636 us; speedup vs baseline: 1.0380x; 1.0380x over previous
//
#include <hip/hip_runtime.h>
#include <hip/hip_bf16.h>

typedef float f32x4 __attribute__((ext_vector_type(4)));
typedef short bf16x8 __attribute__((ext_vector_type(8)));

#define MFMA_BF16 __builtin_amdgcn_mfma_f32_16x16x32_bf16

static __device__ __forceinline__ unsigned short f2bf(float f) {
    __hip_bfloat16 h = __float2bfloat16(f);
    return __builtin_bit_cast(unsigned short, h);
}
static __device__ __forceinline__ unsigned int pack2(float a, float b) {
    return (unsigned int)f2bf(a) | ((unsigned int)f2bf(b) << 16);
}

// Async global->LDS, 16B per lane. LDS dest is wave-uniform base + lane*16.
static __device__ __forceinline__ void gl16(const unsigned short* g, unsigned short* l) {
    unsigned short* gg = const_cast<unsigned short*>(g);
    __builtin_amdgcn_global_load_lds(
        (__attribute__((address_space(1))) unsigned int*)gg,
        (__attribute__((address_space(3))) unsigned int*)l, 16, 0, 0);
}

// ---------------------------------------------------------------------------
// Merged prep: blocks 0..1023 transpose W (f32 k-major -> bf16 n-major);
// blocks 1024..7167 convert q/k/v f32 -> bf16. One launch instead of two.
// ---------------------------------------------------------------------------
__global__ __launch_bounds__(256) void prep_kernel(
    const float* __restrict__ q, const float* __restrict__ k, const float* __restrict__ v,
    const float* __restrict__ Wq, const float* __restrict__ Wk,
    const float* __restrict__ Wv, const float* __restrict__ Wo,
    unsigned short* __restrict__ WT, unsigned short* __restrict__ qkvb)
{
    const int bid = blockIdx.x;
    const int t = threadIdx.x;
    if (bid < 1024) {
        const int z = bid >> 8, rem = bid & 255;
        const int k0 = (rem & 15) * 64, n0 = (rem >> 4) * 64;
        const float* W = (z == 0) ? Wq : (z == 1) ? Wk : (z == 2) ? Wv : Wo;
        unsigned short* Wt = WT + (size_t)z * 1048576;
        __shared__ float tl[64][68];
        const int r = t >> 2, cs = (t & 3) * 16;
#pragma unroll
        for (int j = 0; j < 4; j++)
            *(float4*)&tl[r][cs + j * 4] = *(const float4*)&W[(size_t)(k0 + r) * 1024 + n0 + cs + j * 4];
        __syncthreads();
        const int n = t & 63, kb = (t >> 6) * 16;
#pragma unroll
        for (int j = 0; j < 4; j++) {
            const int kk = kb + j * 4;
            uint2 o = { pack2(tl[kk][n], tl[kk + 1][n]), pack2(tl[kk + 2][n], tl[kk + 3][n]) };
            *(uint2*)&Wt[(size_t)(n0 + n) * 1024 + k0 + kk] = o;
        }
    } else {
        const int idx = bid - 1024;           // 0..6143
        const int z = idx >> 11;              // /2048
        const int xb = idx & 2047;
        const float* s = (z == 0) ? q : (z == 1) ? k : v;
        unsigned short* d = qkvb + (size_t)z * 4194304;
        const size_t i = ((size_t)xb * 256 + t) * 8;
        float4 a = *(const float4*)&s[i], b = *(const float4*)&s[i + 4];
        uint4 o = { pack2(a.x, a.y), pack2(a.z, a.w), pack2(b.x, b.y), pack2(b.z, b.w) };
        *(uint4*)&d[i] = o;
    }
}

// ---------------------------------------------------------------------------
// Shared GEMM core v2: C(128x128) = A(row-major [M][1024] bf16) x Bt^T.
// Triple-buffered LDS, depth-2 prefetch, counted vmcnt(4) + raw barrier.
// ---------------------------------------------------------------------------
static __device__ __forceinline__ void gemm_core(
    const unsigned short* __restrict__ A, const unsigned short* __restrict__ Bt,
    unsigned short* lA, unsigned short* lB, int m0, int n0, f32x4 (&acc)[4][4])
{
    const int t = threadIdx.x;
    const int w = t >> 6, lane = t & 63, lrow = lane & 15, lkg = lane >> 4;
    const int wr = w >> 1, wc = w & 1;
    const int srow = lane >> 2, sseg = (lane & 3) * 8;

    const unsigned short* Ab0 = &A[(size_t)(m0 + w * 32 + srow) * 1024 + sseg];
    const unsigned short* Ab1 = &A[(size_t)(m0 + w * 32 + 16 + srow) * 1024 + sseg];
    const unsigned short* Bb0 = &Bt[(size_t)(n0 + w * 32 + srow) * 1024 + sseg];
    const unsigned short* Bb1 = &Bt[(size_t)(n0 + w * 32 + 16 + srow) * 1024 + sseg];

#define GISSUE(tt, buf)                                     \
    do {                                                    \
        const int k0_ = (tt) * 32;                          \
        gl16(Ab0 + k0_, &lA[(buf) * 4096 + w * 1024]);      \
        gl16(Ab1 + k0_, &lA[(buf) * 4096 + w * 1024 + 512]);\
        gl16(Bb0 + k0_, &lB[(buf) * 4096 + w * 1024]);      \
        gl16(Bb1 + k0_, &lB[(buf) * 4096 + w * 1024 + 512]);\
    } while (0)

    GISSUE(0, 0);
    GISSUE(1, 1);
    __builtin_amdgcn_sched_barrier(0);

    int bcur = 0;
    for (int tt = 0; tt < 32; ++tt) {
        if (tt < 31) { asm volatile("s_waitcnt vmcnt(4)"); }
        else         { asm volatile("s_waitcnt vmcnt(0)"); }
        __builtin_amdgcn_s_barrier();
        __builtin_amdgcn_sched_barrier(0);
        if (tt + 2 < 32) {
            int bpre = bcur + 2; if (bpre >= 3) bpre -= 3;
            GISSUE(tt + 2, bpre);
        }
        __builtin_amdgcn_sched_barrier(0);

        const unsigned short* la = &lA[bcur * 4096];
        const unsigned short* lb = &lB[bcur * 4096];
        bf16x8 af[4], bfr[4];
#pragma unroll
        for (int mi = 0; mi < 4; mi++)
            af[mi] = *(const bf16x8*)&la[(wr * 64 + mi * 16 + lrow) * 32 + lkg * 8];
#pragma unroll
        for (int ni = 0; ni < 4; ni++)
            bfr[ni] = *(const bf16x8*)&lb[(wc * 64 + ni * 16 + lrow) * 32 + lkg * 8];
        __builtin_amdgcn_s_setprio(1);
#pragma unroll
        for (int mi = 0; mi < 4; mi++)
#pragma unroll
            for (int ni = 0; ni < 4; ni++)
                acc[mi][ni] = MFMA_BF16(af[mi], bfr[ni], acc[mi][ni], 0, 0, 0);
        __builtin_amdgcn_s_setprio(0);
        bcur = (bcur == 2) ? 0 : bcur + 1;
    }
#undef GISSUE
}

// ---------------------------------------------------------------------------
// QKV projections, 1D XCD-chunked grid (768 = 8 XCD x 96).
// z=0: Q->[B,H,L,64]; z=1: K->[B,H,L,64]; z=2: V->[B,H,64,L].
// ---------------------------------------------------------------------------
__global__ __launch_bounds__(256) void gemm_qkv(
    const unsigned short* __restrict__ qkvb, const unsigned short* __restrict__ WT,
    const float* __restrict__ bq, const float* __restrict__ bk, const float* __restrict__ bv,
    unsigned short* __restrict__ Qh, unsigned short* __restrict__ Kh, unsigned short* __restrict__ Vt)
{
    const int u0 = blockIdx.x;
    const int u = (u0 & 7) * 96 + (u0 >> 3);       // XCD-contiguous chunks
    const int z = u >> 8, rm = u & 255;
    const int m0 = ((rm >> 3) & 31) * 128, n0 = (rm & 7) * 128;

    const unsigned short* A = qkvb + (size_t)z * 4194304;
    const unsigned short* Bt = WT + (size_t)z * 1048576;
    const float* bias = (z == 0) ? bq : (z == 1) ? bk : bv;

    __shared__ unsigned short lA[3 * 4096], lB[3 * 4096];
    f32x4 acc[4][4];
#pragma unroll
    for (int i = 0; i < 4; i++)
#pragma unroll
        for (int j = 0; j < 4; j++) acc[i][j] = (f32x4){0.f, 0.f, 0.f, 0.f};

    gemm_core(A, Bt, lA, lB, m0, n0, acc);

    const int t = threadIdx.x;
    const int w = t >> 6, lane = t & 63, lrow = lane & 15, lkg = lane >> 4;
    const int wr = w >> 1, wc = w & 1;

#pragma unroll
    for (int mi = 0; mi < 4; mi++) {
#pragma unroll
        for (int ni = 0; ni < 4; ni++) {
            const int gn = n0 + wc * 64 + ni * 16 + lrow;
            const float bb = bias[gn];
            const int hh = gn >> 6, dk = gn & 63;
            const int gm0 = m0 + wr * 64 + mi * 16 + lkg * 4;
            const int b2 = gm0 >> 11, ll = gm0 & 2047;
            if (z < 2) {
                unsigned short* C = (z == 0) ? Qh : Kh;
#pragma unroll
                for (int r = 0; r < 4; r++)
                    C[(size_t)((b2 * 16 + hh) * 2048 + ll + r) * 64 + dk] = f2bf(acc[mi][ni][r] + bb);
            } else {
                uint2 o = { pack2(acc[mi][ni][0] + bb, acc[mi][ni][1] + bb),
                            pack2(acc[mi][ni][2] + bb, acc[mi][ni][3] + bb) };
                *(uint2*)&Vt[(size_t)((b2 * 16 + hh) * 64 + dk) * 2048 + ll] = o;
            }
        }
    }
}

// ---------------------------------------------------------------------------
// Output projection, 1D XCD-chunked grid (256 = 8 x 32).
// ---------------------------------------------------------------------------
__global__ __launch_bounds__(256) void gemm_o(
    const unsigned short* __restrict__ Oh, const unsigned short* __restrict__ WoT,
    const float* __restrict__ bo, float* __restrict__ out)
{
    const int u0 = blockIdx.x;
    const int u = (u0 & 7) * 32 + (u0 >> 3);
    const int m0 = (u >> 3) * 128, n0 = (u & 7) * 128;

    __shared__ unsigned short lA[3 * 4096], lB[3 * 4096];
    f32x4 acc[4][4];
#pragma unroll
    for (int i = 0; i < 4; i++)
#pragma unroll
        for (int j = 0; j < 4; j++) acc[i][j] = (f32x4){0.f, 0.f, 0.f, 0.f};

    gemm_core(Oh, WoT, lA, lB, m0, n0, acc);

    const int t = threadIdx.x;
    const int w = t >> 6, lane = t & 63, lrow = lane & 15, lkg = lane >> 4;
    const int wr = w >> 1, wc = w & 1;

#pragma unroll
    for (int mi = 0; mi < 4; mi++) {
#pragma unroll
        for (int ni = 0; ni < 4; ni++) {
            const int gn = n0 + wc * 64 + ni * 16 + lrow;
            const float bb = bo[gn];
            const int gm0 = m0 + wr * 64 + mi * 16 + lkg * 4;
#pragma unroll
            for (int r = 0; r < 4; r++)
                out[(size_t)(gm0 + r) * 1024 + gn] = acc[mi][ni][r] + bb;
        }
    }
}

// ---------------------------------------------------------------------------
// Fused attention v4 (R13, best-known): Q-tile 64, 4 waves, 1024 blocks, 4/CU.
// LDS 32KB: regA 16KB (sweep1 buf0 / sweep2 f32 stage) + kv 16KB.
// Sweep 1: KVBLK=128 dbuf regA/kv, 16 tiles/barriers; last tile issues
// sweep-2 tile 0 into kv. Sweep 2: single kv buffer, per tile: QK ->
// exp->stage -> PV -> barrier1 -> issue loads(t+1) -> transposed 256B
// nt-stores -> vmcnt(4) -> barrier2.
// ---------------------------------------------------------------------------
__global__ __launch_bounds__(256, 4) void attn_kernel(
    const unsigned short* __restrict__ Qh, const unsigned short* __restrict__ Kh,
    const unsigned short* __restrict__ Vt, float* __restrict__ attn,
    unsigned short* __restrict__ Oh)
{
    const int bid = blockIdx.x;
    const int swz = (bid & 7) * 128 + (bid >> 3);    // XCD-contiguous (1024 = 8*128)
    const int bh = swz >> 5;
    const int q0 = (swz & 31) * 64;
    const int b = bh >> 4, h = bh & 15;
    const int t = threadIdx.x;
    const int w = t >> 6, lane = t & 63, ql = lane & 15, kg = lane >> 4;

    __shared__ unsigned short regA[8192];    // 16KB: sweep1 buf0 / sweep2 f32 stage
    __shared__ unsigned short kv[8192];      // 16KB: sweep1 buf1 / sweep2 K+V

    const size_t kvbase = (size_t)bh * 2048 * 64;
    const float C = 0.18033688011112042f;    // 0.125 * log2(e)

    const unsigned short* qptr = Qh + kvbase + (size_t)(q0 + w * 16 + ql) * 64 + kg * 8;
    const bf16x8 qf0 = *(const bf16x8*)(qptr);
    const bf16x8 qf1 = *(const bf16x8*)(qptr + 32);

    const unsigned short* Kbh = Kh + kvbase;
    const unsigned short* Vbh = Vt + kvbase;

    // sweep-2 staging coords: wave w covers rows kr, kr+8 (pre-swizzled col16)
    const int kr = w * 16 + (lane >> 3);
    const int kc = (lane & 7) ^ (kr & 7);
    // sweep-1 staging coords: wave w covers rows kr2 + 8i, i=0..3 (128-row tile)
    const int kr2 = w * 32 + (lane >> 3);
    const int kc2 = (lane & 7) ^ (kr2 & 7);  // (kr2+8i)&7 == kr2&7
    const int r7 = ql & 7;

    // ---- sweep 1: denominators (K tiles of 128 rows, dbuf regA/kv) ----
    f32x4 ls4 = (f32x4){0.f, 0.f, 0.f, 0.f};
    {
#pragma unroll
        for (int i = 0; i < 4; i++)
            gl16(Kbh + (size_t)(kr2 + 8 * i) * 64 + kc2 * 8, &regA[w * 2048 + i * 512]);
        __syncthreads();
        for (int kt = 0; kt < 16; ++kt) {
            unsigned short* nbuf = (kt & 1) ? regA : kv;       // dest for tile kt+1
            if (kt < 15) {
                const int k0n = (kt + 1) * 128;
#pragma unroll
                for (int i = 0; i < 4; i++)
                    gl16(Kbh + (size_t)(k0n + kr2 + 8 * i) * 64 + kc2 * 8, &nbuf[w * 2048 + i * 512]);
            }
            const unsigned short* Kl = (kt & 1) ? kv : regA;
            f32x4 sacc[8];
            __builtin_amdgcn_s_setprio(1);
#pragma unroll
            for (int ni = 0; ni < 8; ni++) {
                const int rb = (ni * 16 + ql) * 64;
                bf16x8 kf0 = *(const bf16x8*)&Kl[rb + ((kg ^ r7) * 8)];
                bf16x8 kf1 = *(const bf16x8*)&Kl[rb + (((4 + kg) ^ r7) * 8)];
                f32x4 s = (f32x4){0.f, 0.f, 0.f, 0.f};
                s = MFMA_BF16(kf0, qf0, s, 0, 0, 0);
                sacc[ni] = MFMA_BF16(kf1, qf1, s, 0, 0, 0);
            }
            __builtin_amdgcn_s_setprio(0);
#pragma unroll
            for (int ni = 0; ni < 8; ni++)
#pragma unroll
                for (int r = 0; r < 4; r++) ls4[r] += exp2f(sacc[ni][r] * C);
            __syncthreads();
        }
        // issue sweep-2 tile 0 into kv (K rows kr,kr+8 + V rows kr,kr+8)
        gl16(Kbh + (size_t)kr * 64 + kc * 8, &kv[w * 1024]);
        gl16(Kbh + (size_t)(kr + 8) * 64 + kc * 8, &kv[w * 1024 + 512]);
        gl16(Vbh + (size_t)kr * 2048 + kc * 8, &kv[4096 + w * 1024]);
        gl16(Vbh + (size_t)(kr + 8) * 2048 + kc * 8, &kv[4096 + w * 1024 + 512]);
    }
    float lsum = ls4[0] + ls4[1] + ls4[2] + ls4[3];
    lsum += __shfl_xor(lsum, 16);
    lsum += __shfl_xor(lsum, 32);
    const float mlg = -log2f(lsum);          // p = exp2(S*C - log2 l)
    __syncthreads();                         // vmcnt(0): sweep-2 tile 0 landed

    // ---- sweep 2: attn write + PV (K+V tiles of 64, single kv buffer) ----
    f32x4 acco[4];
#pragma unroll
    for (int nv = 0; nv < 4; nv++) acco[nv] = (f32x4){0.f, 0.f, 0.f, 0.f};

    float* stgW = (float*)regA + w * 1024;   // per-wave [16 q][64 k] f32 stage
    const unsigned short* kvK = kv;
    const unsigned short* kvV = kv + 4096;
    float* abase = attn + ((size_t)bh * 2048 + q0 + w * 16) * 2048 + ql * 4;

    for (int kt = 0; kt < 32; ++kt) {
        const int k0 = kt * 64;

        f32x4 sacc[4];
        __builtin_amdgcn_s_setprio(1);
#pragma unroll
        for (int ni = 0; ni < 4; ni++) {
            const int rb = (ni * 16 + ql) * 64;
            bf16x8 kf0 = *(const bf16x8*)&kvK[rb + ((kg ^ r7) * 8)];
            bf16x8 kf1 = *(const bf16x8*)&kvK[rb + (((4 + kg) ^ r7) * 8)];
            f32x4 s = (f32x4){0.f, 0.f, 0.f, 0.f};
            s = MFMA_BF16(kf0, qf0, s, 0, 0, 0);
            sacc[ni] = MFMA_BF16(kf1, qf1, s, 0, 0, 0);
        }
        __builtin_amdgcn_s_setprio(0);

#pragma unroll
        for (int ni = 0; ni < 4; ni++) {
            f32x4 p;
#pragma unroll
            for (int r = 0; r < 4; r++) p[r] = exp2f(fmaf(sacc[ni][r], C, mlg));
            *(f32x4*)&stgW[ql * 64 + ni * 16 + kg * 4] = p;
        }

        __builtin_amdgcn_s_setprio(1);
#pragma unroll
        for (int s4 = 0; s4 < 2; s4++) {
            const float* ps = &stgW[ql * 64 + s4 * 32 + kg * 8];
            f32x4 pa = *(const f32x4*)ps;
            f32x4 pb = *(const f32x4*)(ps + 4);
            uint4 pw = { pack2(pa[0], pa[1]), pack2(pa[2], pa[3]),
                         pack2(pb[0], pb[1]), pack2(pb[2], pb[3]) };
            bf16x8 pf = __builtin_bit_cast(bf16x8, pw);
#pragma unroll
            for (int nv = 0; nv < 4; nv++) {
                const int cc = (s4 * 4 + kg) ^ r7;
                bf16x8 vf = *(const bf16x8*)&kvV[(nv * 16 + ql) * 64 + cc * 8];
                acco[nv] = MFMA_BF16(vf, pf, acco[nv], 0, 0, 0);
            }
        }
        __builtin_amdgcn_s_setprio(0);

        __builtin_amdgcn_s_barrier();        // all waves done reading kv
        __builtin_amdgcn_sched_barrier(0);

        if (kt < 31) {
            const int k0n = (kt + 1) * 64;
            gl16(Kbh + (size_t)(k0n + kr) * 64 + kc * 8, &kv[w * 1024]);
            gl16(Kbh + (size_t)(k0n + kr + 8) * 64 + kc * 8, &kv[w * 1024 + 512]);
            gl16(Vbh + (size_t)kr * 2048 + k0n + kc * 8, &kv[4096 + w * 1024]);
            gl16(Vbh + (size_t)(kr + 8) * 2048 + k0n + kc * 8, &kv[4096 + w * 1024 + 512]);
        }
        __builtin_amdgcn_sched_barrier(0);

#pragma unroll
        for (int i = 0; i < 4; i++) {
            const int row = i * 4 + kg;
            f32x4 vv = *(const f32x4*)&stgW[row * 64 + ql * 4];
            __builtin_nontemporal_store(vv, (f32x4*)&abase[(size_t)row * 2048 + k0]);
        }

        asm volatile("s_waitcnt vmcnt(4)");
        __builtin_amdgcn_s_barrier();        // all waves' loads landed
        __builtin_amdgcn_sched_barrier(0);
    }
    asm volatile("s_waitcnt vmcnt(0)");

    unsigned short* obase = Oh + ((size_t)(b * 2048 + q0 + w * 16 + ql)) * 1024 + h * 64 + kg * 4;
#pragma unroll
    for (int nv = 0; nv < 4; nv++) {
        uint2 o2 = { pack2(acco[nv][0], acco[nv][1]), pack2(acco[nv][2], acco[nv][3]) };
        *(uint2*)&obase[nv * 16] = o2;
    }
}

// ---------------------------------------------------------------------------
extern "C" void kernel_launch(void* const* d_in, const int* in_sizes, int n_in,
                              void* d_out, int out_size, void* d_ws, size_t ws_size,
                              hipStream_t stream) {
    const float* q  = (const float*)d_in[0];
    const float* k  = (const float*)d_in[1];
    const float* v  = (const float*)d_in[2];
    const float* Wq = (const float*)d_in[3];
    const float* bq = (const float*)d_in[4];
    const float* Wk = (const float*)d_in[5];
    const float* bk = (const float*)d_in[6];
    const float* Wv = (const float*)d_in[7];
    const float* bv = (const float*)d_in[8];
    const float* Wo = (const float*)d_in[9];
    const float* bo = (const float*)d_in[10];

    float* out  = (float*)d_out;                    // [2,2048,1024]
    float* attn = out + (size_t)2 * 2048 * 1024;    // [2,16,2048,2048]

    const size_t HS = 4194304;                      // 2*16*2048*64
    unsigned short* qkvb = (unsigned short*)d_ws;   // 3*HS bf16
    unsigned short* WT   = qkvb + 3 * HS;           // 4 * 1M bf16
    unsigned short* Qh   = WT + 4 * 1048576;        // [B,H,L,64]
    unsigned short* Kh   = Qh + HS;                 // [B,H,L,64]
    unsigned short* Vt   = Kh + HS;                 // [B,H,64,L]
    unsigned short* Oh   = Vt + HS;                 // [B,L,1024]

    prep_kernel<<<dim3(7168), 256, 0, stream>>>(q, k, v, Wq, Wk, Wv, Wo, WT, qkvb);
    gemm_qkv   <<<dim3(768),  256, 0, stream>>>(qkvb, WT, bq, bk, bv, Qh, Kh, Vt);
    attn_kernel<<<dim3(1024), 256, 0, stream>>>(Qh, Kh, Vt, attn, Oh);
    gemm_o     <<<dim3(256),  256, 0, stream>>>(Oh, WT + 3 * 1048576, bo, out);
}